// Round 4
// baseline (376.164 us; speedup 1.0000x reference)
//
#include <hip/hip_runtime.h>

typedef _Float16 v8hf __attribute__((ext_vector_type(8)));
typedef float    v4f  __attribute__((ext_vector_type(4)));

#define MFMA16(a, b, c) __builtin_amdgcn_mfma_f32_16x16x32_f16((a), (b), (c), 0, 0, 0)

#define TT 512
#define BT 16      // batch rows per workgroup (= MFMA M)
#define NTH 256    // 4 waves, one per SIMD

// h1 k-layout: 0..99 = h1, 100..111 = fake neurons (0), 112..113 = x_t, 114..135 = 0.
__shared__ __align__(16) _Float16 h1b[2][BT][136];
__shared__ __align__(16) _Float16 h2b[2][BT][72];
__shared__ __align__(16) _Float16 h3b[2][BT][40];
__shared__ __align__(16) _Float16 xst[TT][2 * BT];   // [t][b*2+c]
__shared__ __align__(16) float    oring[BT][64][2];  // head output ring [b][t&63][c]

// batched tanh: 4 exp2 + 1 rcp for 4 values. clamp |x|<=4.8 (err 1.35e-4).
__device__ __forceinline__ v4f tanh4(v4f r) {
    const float KS = 2.8853900817779268f;   // 2*log2(e)
    const float CL = 13.8498724f;           // 4.8 * KS
    float z0 = fminf(CL, fmaxf(-CL, r[0] * KS));
    float z1 = fminf(CL, fmaxf(-CL, r[1] * KS));
    float z2 = fminf(CL, fmaxf(-CL, r[2] * KS));
    float z3 = fminf(CL, fmaxf(-CL, r[3] * KS));
    float a0 = __builtin_amdgcn_exp2f(z0) + 1.f;
    float a1 = __builtin_amdgcn_exp2f(z1) + 1.f;
    float a2 = __builtin_amdgcn_exp2f(z2) + 1.f;
    float a3 = __builtin_amdgcn_exp2f(z3) + 1.f;
    float P = a0 * a1, Q = a2 * a3;
    float R = __builtin_amdgcn_rcpf(P * Q);
    float iP = Q * R, iQ = P * R;           // 1/(a0*a1), 1/(a2*a3)
    v4f t;
    t[0] = 1.f - 2.f * (a1 * iP);
    t[1] = 1.f - 2.f * (a0 * iP);
    t[2] = 1.f - 2.f * (a3 * iQ);
    t[3] = 1.f - 2.f * (a2 * iQ);
    return t;
}

__global__ __launch_bounds__(NTH)
void rnn3_w4(const float* __restrict__ xg,
             const float* __restrict__ Wih1, const float* __restrict__ Whh1,
             const float* __restrict__ bih1, const float* __restrict__ bhh1,
             const float* __restrict__ Wih2, const float* __restrict__ Whh2,
             const float* __restrict__ bih2, const float* __restrict__ bhh2,
             const float* __restrict__ Wih3, const float* __restrict__ Whh3,
             const float* __restrict__ bih3, const float* __restrict__ bhh3,
             const float* __restrict__ Wo1,  const float* __restrict__ bo1,
             const float* __restrict__ Wo2,  const float* __restrict__ bo2,
             float* __restrict__ outg)
{
    const int tid   = threadIdx.x;
    const int lane  = tid & 63;
    const int wid   = tid >> 6;       // wave 0..3
    const int col   = lane & 15;      // MFMA 16-lane index
    const int g     = lane >> 4;      // k-group 0..3
    const int bbase = blockIdx.x * BT;

    // ---------------- init: zero state buffers, stage x ----------------
    {
        _Float16* z1 = &h1b[0][0][0];
        for (int i = tid; i < 2 * BT * 136; i += NTH) z1[i] = (_Float16)0.f;
        _Float16* z2 = &h2b[0][0][0];
        for (int i = tid; i < 2 * BT * 72; i += NTH) z2[i] = (_Float16)0.f;
        _Float16* z3 = &h3b[0][0][0];
        for (int i = tid; i < 2 * BT * 40; i += NTH) z3[i] = (_Float16)0.f;
        for (int i = tid; i < BT * TT * 2; i += NTH) {
            float v = xg[(size_t)bbase * (TT * 2) + i];
            int b = i >> 10, r = i & 1023, t = r >> 1, c = r & 1;
            xst[t][b * 2 + c] = (_Float16)v;
        }
    }

    // ---------------- weight fragments (registers) ----------------
    // B-frag convention: (lane,e) = W[j][k], j = 16*tile + col, k = kt*32 + g*8 + e.
    v8hf F[16];
    #pragma unroll
    for (int i = 0; i < 16; ++i) F[i] = (v8hf)(_Float16)0.f;
    float bb0 = 0.f, bb1 = 0.f, bb2 = 0.f, bb3 = 0.f;

    auto ldW = [&](const float* W, int rows, int cols, int j, int kt) -> v8hf {
        v8hf r;
        #pragma unroll
        for (int e = 0; e < 8; ++e) {
            const int k = kt * 32 + g * 8 + e;
            float v = (j < rows && k < cols) ? W[j * cols + k] : 0.f;
            r[e] = (_Float16)v;
        }
        return r;
    };
    auto ldW1 = [&](int j, int kt) -> v8hf {     // Whh1 (k<100) + x weights at k=112,113
        v8hf r;
        #pragma unroll
        for (int e = 0; e < 8; ++e) {
            const int k = kt * 32 + g * 8 + e;
            float v = 0.f;
            if (j < 100) {
                if (k < 100)       v = Whh1[j * 100 + k];
                else if (k == 112) v = Wih1[j * 2];
                else if (k == 113) v = Wih1[j * 2 + 1];
            }
            r[e] = (_Float16)v;
        }
        return r;
    };
    auto bL1 = [&](int j) -> float { return (j < 100) ? bih1[j] + bhh1[j] : 0.f; };
    auto bL2 = [&](int j) -> float { return (j < 60) ? bih2[j] + bhh2[j] : 0.f; };
    auto bL3 = [&](int j) -> float { return (j < 30) ? bih3[j] + bhh3[j] : 0.f; };

    if (wid == 0) {                    // L1 tiles 0,1,2 + L3 tile 1
        #pragma unroll
        for (int kt = 0; kt < 4; ++kt) {
            F[0 + kt] = ldW1(col, kt);
            F[4 + kt] = ldW1(col + 16, kt);
            F[8 + kt] = ldW1(col + 32, kt);
        }
        F[12] = ldW(Wih3, 30, 60, col + 16, 0);
        F[13] = ldW(Wih3, 30, 60, col + 16, 1);
        F[14] = ldW(Whh3, 30, 30, col + 16, 0);
        bb0 = bL1(col); bb1 = bL1(col + 16); bb2 = bL1(col + 32); bb3 = bL3(col + 16);
    } else if (wid == 1) {             // L1 tiles 3,4,5 + head
        #pragma unroll
        for (int kt = 0; kt < 4; ++kt) {
            F[0 + kt] = ldW1(col + 48, kt);
            F[4 + kt] = ldW1(col + 64, kt);
            F[8 + kt] = ldW1(col + 80, kt);
        }
        #pragma unroll
        for (int e = 0; e < 8; ++e) {  // W_eff = Wo2 @ Wo1 (2 x 30)
            const int k = g * 8 + e;
            float v = 0.f;
            if (col < 2 && k < 30) {
                #pragma unroll
                for (int u = 0; u < 10; ++u) v += Wo2[col * 10 + u] * Wo1[u * 30 + k];
            }
            F[12][e] = (_Float16)v;
        }
        bb0 = bL1(col + 48); bb1 = bL1(col + 64); bb2 = bL1(col + 80);
        if (col < 2) {
            float bv = bo2[col];
            #pragma unroll
            for (int u = 0; u < 10; ++u) bv += Wo2[col * 10 + u] * bo1[u];
            bb3 = bv;
        }
    } else if (wid == 2) {             // L2 tiles 0,1 + L3 tile 0
        #pragma unroll
        for (int kt = 0; kt < 4; ++kt) {
            F[0 + kt] = ldW(Wih2, 60, 100, col, kt);
            F[6 + kt] = ldW(Wih2, 60, 100, col + 16, kt);
        }
        F[4]  = ldW(Whh2, 60, 60, col, 0);       F[5]  = ldW(Whh2, 60, 60, col, 1);
        F[10] = ldW(Whh2, 60, 60, col + 16, 0);  F[11] = ldW(Whh2, 60, 60, col + 16, 1);
        F[12] = ldW(Wih3, 30, 60, col, 0);
        F[13] = ldW(Wih3, 30, 60, col, 1);
        F[14] = ldW(Whh3, 30, 30, col, 0);
        bb0 = bL2(col); bb1 = bL2(col + 16); bb2 = bL3(col);
    } else {                           // L1 tile 6 + L2 tiles 2,3 + x-stage
        #pragma unroll
        for (int kt = 0; kt < 4; ++kt) {
            F[0 + kt]  = ldW1(col + 96, kt);
            F[4 + kt]  = ldW(Wih2, 60, 100, col + 32, kt);
            F[10 + kt] = ldW(Wih2, 60, 100, col + 48, kt);
        }
        F[8]  = ldW(Whh2, 60, 60, col + 32, 0);  F[9]  = ldW(Whh2, 60, 60, col + 32, 1);
        F[14] = ldW(Whh2, 60, 60, col + 48, 0);  F[15] = ldW(Whh2, 60, 60, col + 48, 1);
        bb0 = bL1(col + 96); bb1 = bL2(col + 32); bb2 = bL2(col + 48);
    }

    __syncthreads();
    if (tid < BT)   // x_0 into h1 buffer parity 0 at k=112..113
        *(unsigned*)&h1b[0][tid][112] = *(const unsigned*)&xst[0][tid * 2];
    __syncthreads();

#define WR_H1(r, jw) { _Pragma("unroll") for (int i = 0; i < 4; ++i) h1b[wp][4*g+i][jw] = (_Float16)(r)[i]; }
#define WR_H2(r, jw) { _Pragma("unroll") for (int i = 0; i < 4; ++i) h2b[rp][4*g+i][jw] = (_Float16)(r)[i]; }
#define WR_H3(r, jw) { _Pragma("unroll") for (int i = 0; i < 4; ++i) h3b[wp][4*g+i][jw] = (_Float16)(r)[i]; }

#define L1_TILE(f0, f1, f2, f3, bias, jw) { \
    v4f p = {bias, bias, bias, bias}, q = {0.f, 0.f, 0.f, 0.f}; \
    p = MFMA16(A0, f0, p); q = MFMA16(A1, f1, q); \
    p = MFMA16(A2, f2, p); q = MFMA16(A3, f3, q); \
    v4f r = tanh4(p + q); WR_H1(r, jw); }

#define L2_TILE(f0, f1, f2, f3, f4, f5, bias, jw) { \
    v4f p = {bias, bias, bias, bias}, q = {0.f, 0.f, 0.f, 0.f}; \
    p = MFMA16(A0, f0, p); q = MFMA16(A1, f1, q); \
    p = MFMA16(A2, f2, p); q = MFMA16(A3, f3, q); \
    p = MFMA16(B0, f4, p); q = MFMA16(B1, f5, q); \
    v4f r = tanh4(p + q); WR_H2(r, jw); }

#define L3_TILE(f0, f1, f2, bias, jw) { \
    v4f p = {bias, bias, bias, bias}, q = {0.f, 0.f, 0.f, 0.f}; \
    p = MFMA16(B0, f0, p); q = MFMA16(B1, f1, q); \
    p = MFMA16(C0, f2, p); \
    v4f r = tanh4(p + q); WR_H3(r, jw); }

    // ---------------- pipelined loop: one barrier per phase ----------------
    // phase s: L1(s) | L2(s-1) | L3(s-2) | head(s-3)
    for (int s = 0; s < TT + 3; ++s) {
        const int rp = s & 1, wp = rp ^ 1;
        const _Float16* h1p = &h1b[rp][col][g * 8];
        const _Float16* h2p = &h2b[wp][col][g * 8];   // h2(s-2)
        const _Float16* h3p = &h3b[rp][col][g * 8];   // h3(s-3)

        if (wid == 0) {
            v8hf A0 = *(const v8hf*)(h1p);      v8hf A1 = *(const v8hf*)(h1p + 32);
            v8hf A2 = *(const v8hf*)(h1p + 64); v8hf A3 = *(const v8hf*)(h1p + 96);
            v8hf B0 = *(const v8hf*)(h2p);      v8hf B1 = *(const v8hf*)(h2p + 32);
            v8hf C0 = *(const v8hf*)(h3p);
            if (s < TT) {
                L1_TILE(F[0], F[1], F[2], F[3],   bb0, col);
                L1_TILE(F[4], F[5], F[6], F[7],   bb1, col + 16);
                L1_TILE(F[8], F[9], F[10], F[11], bb2, col + 32);
            }
            if (s >= 2 && s <= TT + 1) L3_TILE(F[12], F[13], F[14], bb3, col + 16);
        } else if (wid == 1) {
            v8hf A0 = *(const v8hf*)(h1p);      v8hf A1 = *(const v8hf*)(h1p + 32);
            v8hf A2 = *(const v8hf*)(h1p + 64); v8hf A3 = *(const v8hf*)(h1p + 96);
            v8hf C0 = *(const v8hf*)(h3p);
            if (s < TT) {
                L1_TILE(F[0], F[1], F[2], F[3],   bb0, col + 48);
                L1_TILE(F[4], F[5], F[6], F[7],   bb1, col + 64);
                L1_TILE(F[8], F[9], F[10], F[11], bb2, col + 80);
            }
            if (s >= 3) {                      // head for t = s-3
                const int t = s - 3;
                v4f o = {bb3, bb3, bb3, bb3};
                o = MFMA16(C0, F[12], o);
                if (col < 2) {
                    #pragma unroll
                    for (int i = 0; i < 4; ++i) oring[4 * g + i][t & 63][col] = o[i];
                }
                if ((t & 63) == 63) {          // coalesced flush of 64 steps
                    const int tbase = t - 63;
                    const float4* ring4 = (const float4*)&oring[0][0][0];
                    #pragma unroll
                    for (int jj = 0; jj < 8; ++jj) {
                        const int f = lane + 64 * jj;
                        const int b = f >> 5, k = f & 31;
                        float4 v = ring4[f];
                        *(float4*)(outg + ((size_t)(bbase + b) * TT + tbase) * 2 + 4 * k) = v;
                    }
                }
            }
        } else if (wid == 2) {
            v8hf A0 = *(const v8hf*)(h1p);      v8hf A1 = *(const v8hf*)(h1p + 32);
            v8hf A2 = *(const v8hf*)(h1p + 64); v8hf A3 = *(const v8hf*)(h1p + 96);
            v8hf B0 = *(const v8hf*)(h2p);      v8hf B1 = *(const v8hf*)(h2p + 32);
            v8hf C0 = *(const v8hf*)(h3p);
            if (s >= 1 && s <= TT) {
                L2_TILE(F[0], F[1], F[2], F[3], F[4], F[5],   bb0, col);
                L2_TILE(F[6], F[7], F[8], F[9], F[10], F[11], bb1, col + 16);
            }
            if (s >= 2 && s <= TT + 1) L3_TILE(F[12], F[13], F[14], bb2, col);
        } else {
            if (lane < BT && s < TT - 1)       // stage x_{s+1}
                *(unsigned*)&h1b[wp][lane][112] = *(const unsigned*)&xst[s + 1][2 * lane];
            v8hf A0 = *(const v8hf*)(h1p);      v8hf A1 = *(const v8hf*)(h1p + 32);
            v8hf A2 = *(const v8hf*)(h1p + 64); v8hf A3 = *(const v8hf*)(h1p + 96);
            v8hf B0 = *(const v8hf*)(h2p);      v8hf B1 = *(const v8hf*)(h2p + 32);
            if (s < TT)
                L1_TILE(F[0], F[1], F[2], F[3], bb0, col + 96);
            if (s >= 1 && s <= TT) {
                L2_TILE(F[4], F[5], F[6], F[7], F[8], F[9],     bb1, col + 32);
                L2_TILE(F[10], F[11], F[12], F[13], F[14], F[15], bb2, col + 48);
            }
        }
        __syncthreads();
    }
}

extern "C" void kernel_launch(void* const* d_in, const int* in_sizes, int n_in,
                              void* d_out, int out_size, void* d_ws, size_t ws_size,
                              hipStream_t stream) {
    (void)in_sizes; (void)n_in; (void)d_ws; (void)ws_size; (void)out_size;
    const float* x     = (const float*)d_in[0];
    const float* W_ih1 = (const float*)d_in[1];
    const float* W_hh1 = (const float*)d_in[2];
    const float* b_ih1 = (const float*)d_in[3];
    const float* b_hh1 = (const float*)d_in[4];
    const float* W_ih2 = (const float*)d_in[5];
    const float* W_hh2 = (const float*)d_in[6];
    const float* b_ih2 = (const float*)d_in[7];
    const float* b_hh2 = (const float*)d_in[8];
    const float* W_ih3 = (const float*)d_in[9];
    const float* W_hh3 = (const float*)d_in[10];
    const float* b_ih3 = (const float*)d_in[11];
    const float* b_hh3 = (const float*)d_in[12];
    const float* W_o1  = (const float*)d_in[13];
    const float* b_o1  = (const float*)d_in[14];
    const float* W_o2  = (const float*)d_in[15];
    const float* b_o2  = (const float*)d_in[16];
    float* out = (float*)d_out;

    rnn3_w4<<<2048 / BT, NTH, 0, stream>>>(
        x, W_ih1, W_hh1, b_ih1, b_hh1,
        W_ih2, W_hh2, b_ih2, b_hh2,
        W_ih3, W_hh3, b_ih3, b_hh3,
        W_o1, b_o1, W_o2, b_o2, out);
}

// Round 5
// 322.611 us; speedup vs baseline: 1.1660x; 1.1660x over previous
//
#include <hip/hip_runtime.h>

typedef _Float16 v8hf __attribute__((ext_vector_type(8)));
typedef float    v4f  __attribute__((ext_vector_type(4)));

#define MFMA16(a, b, c) __builtin_amdgcn_mfma_f32_16x16x32_f16((a), (b), (c), 0, 0, 0)

#define TT 512
#define BT 16      // batch rows per workgroup (= MFMA M)
#define NTH 512    // 8 waves, 2 per SIMD

// h1 k-layout: 0..99 = h1, 100..111 = fake neurons (0), 112..113 = x_t, 114..135 = 0.
__shared__ __align__(16) _Float16 h1b[2][BT][136];
__shared__ __align__(16) _Float16 h2b[2][BT][72];
__shared__ __align__(16) _Float16 h3b[2][BT][40];
__shared__ __align__(16) _Float16 xst[TT][2 * BT];    // [t][b*2+c]
__shared__ __align__(16) float    oring[BT][128][2];  // head ring [b][t&127][c]

// batched tanh: 4 exp2 + 1 rcp for 4 values. clamp |x|<=4.8 (err 1.35e-4).
__device__ __forceinline__ v4f tanh4(v4f r) {
    const float KS = 2.8853900817779268f;   // 2*log2(e)
    const float CL = 13.8498724f;           // 4.8 * KS
    float z0 = fminf(CL, fmaxf(-CL, r[0] * KS));
    float z1 = fminf(CL, fmaxf(-CL, r[1] * KS));
    float z2 = fminf(CL, fmaxf(-CL, r[2] * KS));
    float z3 = fminf(CL, fmaxf(-CL, r[3] * KS));
    float a0 = __builtin_amdgcn_exp2f(z0) + 1.f;
    float a1 = __builtin_amdgcn_exp2f(z1) + 1.f;
    float a2 = __builtin_amdgcn_exp2f(z2) + 1.f;
    float a3 = __builtin_amdgcn_exp2f(z3) + 1.f;
    float P = a0 * a1, Q = a2 * a3;
    float R = __builtin_amdgcn_rcpf(P * Q);
    float iP = Q * R, iQ = P * R;           // 1/(a0*a1), 1/(a2*a3)
    v4f t;
    t[0] = 1.f - 2.f * (a1 * iP);
    t[1] = 1.f - 2.f * (a0 * iP);
    t[2] = 1.f - 2.f * (a3 * iQ);
    t[3] = 1.f - 2.f * (a2 * iQ);
    return t;
}

__global__ __launch_bounds__(NTH)
void rnn3_w8(const float* __restrict__ xg,
             const float* __restrict__ Wih1, const float* __restrict__ Whh1,
             const float* __restrict__ bih1, const float* __restrict__ bhh1,
             const float* __restrict__ Wih2, const float* __restrict__ Whh2,
             const float* __restrict__ bih2, const float* __restrict__ bhh2,
             const float* __restrict__ Wih3, const float* __restrict__ Whh3,
             const float* __restrict__ bih3, const float* __restrict__ bhh3,
             const float* __restrict__ Wo1,  const float* __restrict__ bo1,
             const float* __restrict__ Wo2,  const float* __restrict__ bo2,
             float* __restrict__ outg)
{
    const int tid   = threadIdx.x;
    const int lane  = tid & 63;
    const int wid   = tid >> 6;       // wave 0..7
    const int col   = lane & 15;      // MFMA 16-lane index
    const int g     = lane >> 4;      // k-group 0..3
    const int bbase = blockIdx.x * BT;

    // ---------------- init: zero state buffers, stage x ----------------
    {
        _Float16* z1 = &h1b[0][0][0];
        for (int i = tid; i < 2 * BT * 136; i += NTH) z1[i] = (_Float16)0.f;
        _Float16* z2 = &h2b[0][0][0];
        for (int i = tid; i < 2 * BT * 72; i += NTH) z2[i] = (_Float16)0.f;
        _Float16* z3 = &h3b[0][0][0];
        for (int i = tid; i < 2 * BT * 40; i += NTH) z3[i] = (_Float16)0.f;
        for (int i = tid; i < BT * TT * 2; i += NTH) {
            float v = xg[(size_t)bbase * (TT * 2) + i];
            int b = i >> 10, r = i & 1023, t = r >> 1, c = r & 1;
            xst[t][b * 2 + c] = (_Float16)v;
        }
    }

    // ---------------- weight fragments (registers) ----------------
    // B-frag convention: (lane,e) = W[j][k], j = 16*tile + col, k = kt*32 + g*8 + e.
    v8hf F[9];
    #pragma unroll
    for (int i = 0; i < 9; ++i) F[i] = (v8hf)(_Float16)0.f;
    float bb0 = 0.f, bb1 = 0.f;

    auto ldW = [&](const float* W, int rows, int cols, int j, int kt) -> v8hf {
        v8hf r;
        #pragma unroll
        for (int e = 0; e < 8; ++e) {
            const int k = kt * 32 + g * 8 + e;
            float v = (j < rows && k < cols) ? W[j * cols + k] : 0.f;
            r[e] = (_Float16)v;
        }
        return r;
    };
    auto ldW1 = [&](int j, int kt) -> v8hf {     // Whh1 (k<100) + x weights at k=112,113
        v8hf r;
        #pragma unroll
        for (int e = 0; e < 8; ++e) {
            const int k = kt * 32 + g * 8 + e;
            float v = 0.f;
            if (j < 100) {
                if (k < 100)       v = Whh1[j * 100 + k];
                else if (k == 112) v = Wih1[j * 2];
                else if (k == 113) v = Wih1[j * 2 + 1];
            }
            r[e] = (_Float16)v;
        }
        return r;
    };
    auto bL1 = [&](int j) -> float { return (j < 100) ? bih1[j] + bhh1[j] : 0.f; };
    auto bL2 = [&](int j) -> float { return (j < 60) ? bih2[j] + bhh2[j] : 0.f; };
    auto bL3 = [&](int j) -> float { return (j < 30) ? bih3[j] + bhh3[j] : 0.f; };

    if (wid < 3) {                     // L1 tiles 2*wid, 2*wid+1
        const int ja = 32 * wid + col, jb = ja + 16;
        #pragma unroll
        for (int kt = 0; kt < 4; ++kt) { F[0 + kt] = ldW1(ja, kt); F[4 + kt] = ldW1(jb, kt); }
        bb0 = bL1(ja); bb1 = bL1(jb);
    } else if (wid == 3) {             // L1 tile 6 + x-stage + flush
        #pragma unroll
        for (int kt = 0; kt < 4; ++kt) F[kt] = ldW1(col + 96, kt);
        bb0 = bL1(col + 96);
    } else if (wid < 6) {              // L2 tile (wid-4) + L3 tile (wid-4)
        const int j = col + 16 * (wid - 4);
        #pragma unroll
        for (int kt = 0; kt < 4; ++kt) F[kt] = ldW(Wih2, 60, 100, j, kt);
        F[4] = ldW(Whh2, 60, 60, j, 0);  F[5] = ldW(Whh2, 60, 60, j, 1);
        F[6] = ldW(Wih3, 30, 60, j, 0);  F[7] = ldW(Wih3, 30, 60, j, 1);
        F[8] = ldW(Whh3, 30, 30, j, 0);
        bb0 = bL2(j); bb1 = bL3(j);
    } else if (wid == 6) {             // L2 tile 2
        const int j = col + 32;
        #pragma unroll
        for (int kt = 0; kt < 4; ++kt) F[kt] = ldW(Wih2, 60, 100, j, kt);
        F[4] = ldW(Whh2, 60, 60, j, 0);  F[5] = ldW(Whh2, 60, 60, j, 1);
        bb0 = bL2(j);
    } else {                           // L2 tile 3 + head
        const int j = col + 48;
        #pragma unroll
        for (int kt = 0; kt < 4; ++kt) F[kt] = ldW(Wih2, 60, 100, j, kt);
        F[4] = ldW(Whh2, 60, 60, j, 0);  F[5] = ldW(Whh2, 60, 60, j, 1);
        bb0 = bL2(j);
        #pragma unroll
        for (int e = 0; e < 8; ++e) {  // W_eff = Wo2 @ Wo1 (2 x 30)
            const int k = g * 8 + e;
            float v = 0.f;
            if (col < 2 && k < 30) {
                #pragma unroll
                for (int u = 0; u < 10; ++u) v += Wo2[col * 10 + u] * Wo1[u * 30 + k];
            }
            F[6][e] = (_Float16)v;
        }
        if (col < 2) {
            float bv = bo2[col];
            #pragma unroll
            for (int u = 0; u < 10; ++u) bv += Wo2[col * 10 + u] * bo1[u];
            bb1 = bv;
        }
    }

    __syncthreads();
    if (tid < BT)   // x_0 into h1 buffer parity 0 at k=112..113
        *(unsigned*)&h1b[0][tid][112] = *(const unsigned*)&xst[0][tid * 2];
    __syncthreads();

#define WR_H1(r, jw) { _Pragma("unroll") for (int i = 0; i < 4; ++i) h1b[wp][4*g+i][jw] = (_Float16)(r)[i]; }
#define WR_H2(r, jw) { _Pragma("unroll") for (int i = 0; i < 4; ++i) h2b[rp][4*g+i][jw] = (_Float16)(r)[i]; }
#define WR_H3(r, jw) { _Pragma("unroll") for (int i = 0; i < 4; ++i) h3b[wp][4*g+i][jw] = (_Float16)(r)[i]; }

#define L1_TILE(f0, f1, f2, f3, bias, jw) { \
    v4f p = {bias, bias, bias, bias}, q = {0.f, 0.f, 0.f, 0.f}; \
    p = MFMA16(A0, f0, p); q = MFMA16(A1, f1, q); \
    p = MFMA16(A2, f2, p); q = MFMA16(A3, f3, q); \
    v4f r = tanh4(p + q); WR_H1(r, jw); }

#define L2_TILE(f0, f1, f2, f3, f4, f5, bias, jw) { \
    v4f p = {bias, bias, bias, bias}, q = {0.f, 0.f, 0.f, 0.f}; \
    p = MFMA16(A0, f0, p); q = MFMA16(A1, f1, q); \
    p = MFMA16(A2, f2, p); q = MFMA16(A3, f3, q); \
    p = MFMA16(B0, f4, p); q = MFMA16(B1, f5, q); \
    v4f r = tanh4(p + q); WR_H2(r, jw); }

#define L3_TILE(f0, f1, f2, bias, jw) { \
    v4f p = {bias, bias, bias, bias}, q = {0.f, 0.f, 0.f, 0.f}; \
    p = MFMA16(B0, f0, p); q = MFMA16(B1, f1, q); \
    p = MFMA16(C0, f2, p); \
    v4f r = tanh4(p + q); WR_H3(r, jw); }

    // ---------------- pipelined loop: one barrier per phase ----------------
    // phase s: L1(s) | L2(s-1) | L3(s-2) | head(s-3) | flush(block ending s-4)
    for (int s = 0; s < TT + 4; ++s) {
        const int rp = s & 1, wp = rp ^ 1;
        const _Float16* h1p = &h1b[rp][col][g * 8];
        const _Float16* h2p = &h2b[wp][col][g * 8];   // h2(s-2)
        const _Float16* h3p = &h3b[rp][col][g * 8];   // h3(s-3)

        if (wid < 3) {
            v8hf A0 = *(const v8hf*)(h1p);      v8hf A1 = *(const v8hf*)(h1p + 32);
            v8hf A2 = *(const v8hf*)(h1p + 64); v8hf A3 = *(const v8hf*)(h1p + 96);
            if (s < TT) {
                const int j0 = 32 * wid + col;
                L1_TILE(F[0], F[1], F[2], F[3], bb0, j0);
                L1_TILE(F[4], F[5], F[6], F[7], bb1, j0 + 16);
            }
        } else if (wid == 3) {
            if (lane < BT && s < TT - 1)       // stage x_{s+1}
                *(unsigned*)&h1b[wp][lane][112] = *(const unsigned*)&xst[s + 1][2 * lane];
            v8hf A0 = *(const v8hf*)(h1p);      v8hf A1 = *(const v8hf*)(h1p + 32);
            v8hf A2 = *(const v8hf*)(h1p + 64); v8hf A3 = *(const v8hf*)(h1p + 96);
            if (s < TT)
                L1_TILE(F[0], F[1], F[2], F[3], bb0, col + 96);
            if (s >= 67 && ((s - 4) & 63) == 63) {   // flush 64 head steps [s-67, s-4]
                const int tbase = s - 67;
                const int base4 = (tbase & 127) >> 1;    // 0 or 32 (float4 per b-row)
                const float4* ring4 = (const float4*)&oring[0][0][0];
                #pragma unroll
                for (int jj = 0; jj < 8; ++jj) {
                    const int f = lane + 64 * jj;        // 0..511
                    const int b = f >> 5, k = f & 31;
                    float4 v = ring4[b * 64 + base4 + k];
                    *(float4*)(outg + ((size_t)(bbase + b) * TT + tbase) * 2 + 4 * k) = v;
                }
            }
        } else if (wid < 6) {
            v8hf A0 = *(const v8hf*)(h1p);      v8hf A1 = *(const v8hf*)(h1p + 32);
            v8hf A2 = *(const v8hf*)(h1p + 64); v8hf A3 = *(const v8hf*)(h1p + 96);
            v8hf B0 = *(const v8hf*)(h2p);      v8hf B1 = *(const v8hf*)(h2p + 32);
            v8hf C0 = *(const v8hf*)(h3p);
            const int j0 = col + 16 * (wid - 4);
            if (s >= 1 && s <= TT)
                L2_TILE(F[0], F[1], F[2], F[3], F[4], F[5], bb0, j0);
            if (s >= 2 && s <= TT + 1)
                L3_TILE(F[6], F[7], F[8], bb1, j0);
        } else if (wid == 6) {
            v8hf A0 = *(const v8hf*)(h1p);      v8hf A1 = *(const v8hf*)(h1p + 32);
            v8hf A2 = *(const v8hf*)(h1p + 64); v8hf A3 = *(const v8hf*)(h1p + 96);
            v8hf B0 = *(const v8hf*)(h2p);      v8hf B1 = *(const v8hf*)(h2p + 32);
            if (s >= 1 && s <= TT)
                L2_TILE(F[0], F[1], F[2], F[3], F[4], F[5], bb0, col + 32);
        } else {
            v8hf A0 = *(const v8hf*)(h1p);      v8hf A1 = *(const v8hf*)(h1p + 32);
            v8hf A2 = *(const v8hf*)(h1p + 64); v8hf A3 = *(const v8hf*)(h1p + 96);
            v8hf B0 = *(const v8hf*)(h2p);      v8hf B1 = *(const v8hf*)(h2p + 32);
            v8hf C0 = *(const v8hf*)(h3p);
            if (s >= 1 && s <= TT)
                L2_TILE(F[0], F[1], F[2], F[3], F[4], F[5], bb0, col + 48);
            if (s >= 3 && s <= TT + 2) {       // head for t = s-3 -> ring
                const int t = s - 3;
                v4f o = {bb1, bb1, bb1, bb1};
                o = MFMA16(C0, F[6], o);
                if (col < 2) {
                    #pragma unroll
                    for (int i = 0; i < 4; ++i) oring[4 * g + i][t & 127][col] = o[i];
                }
            }
        }
        __syncthreads();
    }
}

extern "C" void kernel_launch(void* const* d_in, const int* in_sizes, int n_in,
                              void* d_out, int out_size, void* d_ws, size_t ws_size,
                              hipStream_t stream) {
    (void)in_sizes; (void)n_in; (void)d_ws; (void)ws_size; (void)out_size;
    const float* x     = (const float*)d_in[0];
    const float* W_ih1 = (const float*)d_in[1];
    const float* W_hh1 = (const float*)d_in[2];
    const float* b_ih1 = (const float*)d_in[3];
    const float* b_hh1 = (const float*)d_in[4];
    const float* W_ih2 = (const float*)d_in[5];
    const float* W_hh2 = (const float*)d_in[6];
    const float* b_ih2 = (const float*)d_in[7];
    const float* b_hh2 = (const float*)d_in[8];
    const float* W_ih3 = (const float*)d_in[9];
    const float* W_hh3 = (const float*)d_in[10];
    const float* b_ih3 = (const float*)d_in[11];
    const float* b_hh3 = (const float*)d_in[12];
    const float* W_o1  = (const float*)d_in[13];
    const float* b_o1  = (const float*)d_in[14];
    const float* W_o2  = (const float*)d_in[15];
    const float* b_o2  = (const float*)d_in[16];
    float* out = (float*)d_out;

    rnn3_w8<<<2048 / BT, NTH, 0, stream>>>(
        x, W_ih1, W_hh1, b_ih1, b_hh1,
        W_ih2, W_hh2, b_ih2, b_hh2,
        W_ih3, W_hh3, b_ih3, b_hh3,
        W_o1, b_o1, W_o2, b_o2, out);
}

// Round 6
// 311.549 us; speedup vs baseline: 1.2074x; 1.0355x over previous
//
#include <hip/hip_runtime.h>

typedef _Float16 v8hf __attribute__((ext_vector_type(8)));
typedef float    v4f  __attribute__((ext_vector_type(4)));

#define MFMA16(a, b, c) __builtin_amdgcn_mfma_f32_16x16x32_f16((a), (b), (c), 0, 0, 0)

#define TT 512
#define BT 16      // batch rows per workgroup (= MFMA M)
#define NTH 512    // 8 waves: w0-3 heavy (1/SIMD), w4-7 light partners

// LDS map (bytes). Two 8KB parity blocks hold all state; parity toggle = addr ^= 8192.
//   block p at p*8192:  h1: +0    row stride 272 B (136 f16; k: 0..99 h1, 100..111 fake,
//                                  112..113 x, rest 0)
//                       h2: +4352 row stride 144 B (72 f16)
//                       h3: +6656 row stride  80 B (40 f16)
//   xst  at 16384: [t][b*2+c] f16, 64 B per t        (32 KB)
//   ring at 49152: [b][64][2] f32, 512 B per b       (8 KB)
#define PBLK  8192u
#define H2OFF 4352u
#define H3OFF 6656u
#define XSTO  16384u
#define RINGO 49152u

__shared__ __align__(64) char SM[57344];

// batched tanh: 4 exp2 + 1 rcp for 4 values; med3 clamp |x|<=4.8 (err 1.35e-4).
__device__ __forceinline__ v4f tanh4(v4f r) {
    const float KS = 2.8853900817779268f;   // 2*log2(e)
    const float CL = 13.8498724f;           // 4.8 * KS
    float z0 = __builtin_amdgcn_fmed3f(r[0] * KS, -CL, CL);
    float z1 = __builtin_amdgcn_fmed3f(r[1] * KS, -CL, CL);
    float z2 = __builtin_amdgcn_fmed3f(r[2] * KS, -CL, CL);
    float z3 = __builtin_amdgcn_fmed3f(r[3] * KS, -CL, CL);
    float a0 = __builtin_amdgcn_exp2f(z0) + 1.f;
    float a1 = __builtin_amdgcn_exp2f(z1) + 1.f;
    float a2 = __builtin_amdgcn_exp2f(z2) + 1.f;
    float a3 = __builtin_amdgcn_exp2f(z3) + 1.f;
    float P = a0 * a1, Q = a2 * a3;
    float R = __builtin_amdgcn_rcpf(P * Q);
    float iP = Q * R, iQ = P * R;
    v4f t;
    t[0] = 1.f - 2.f * (a1 * iP);
    t[1] = 1.f - 2.f * (a0 * iP);
    t[2] = 1.f - 2.f * (a3 * iQ);
    t[3] = 1.f - 2.f * (a2 * iQ);
    return t;
}

__global__ __launch_bounds__(NTH)
void rnn3_hl(const float* __restrict__ xg,
             const float* __restrict__ Wih1, const float* __restrict__ Whh1,
             const float* __restrict__ bih1, const float* __restrict__ bhh1,
             const float* __restrict__ Wih2, const float* __restrict__ Whh2,
             const float* __restrict__ bih2, const float* __restrict__ bhh2,
             const float* __restrict__ Wih3, const float* __restrict__ Whh3,
             const float* __restrict__ bih3, const float* __restrict__ bhh3,
             const float* __restrict__ Wo1,  const float* __restrict__ bo1,
             const float* __restrict__ Wo2,  const float* __restrict__ bo2,
             float* __restrict__ outg)
{
    const int tid   = threadIdx.x;
    const int lane  = tid & 63;
    const int wid   = tid >> 6;       // wave 0..7; SIMD = wid&3 -> pairs (0,4)(1,5)(2,6)(3,7)
    const int col   = lane & 15;
    const int g     = lane >> 4;
    const int bbase = blockIdx.x * BT;

    // ---------------- init: zero both parity state blocks, stage x ----------------
    {
        float4 z = {0.f, 0.f, 0.f, 0.f};
        float4* p4 = (float4*)SM;
        for (int i = tid; i < 1024; i += NTH) p4[i] = z;   // bytes [0, 16384)
        for (int i = tid; i < BT * TT * 2; i += NTH) {
            float v = xg[(size_t)bbase * (TT * 2) + i];
            int b = i >> 10, r = i & 1023, t = r >> 1, c = r & 1;
            *(_Float16*)(SM + XSTO + (unsigned)t * 64u + (unsigned)b * 4u + (unsigned)c * 2u) = (_Float16)v;
        }
    }

    // ---------------- weight fragments (registers) ----------------
    // B-frag convention: (lane,e) = W[j][k], j = tile_base + col, k = kt*32 + g*8 + e.
    v8hf F[14];
    #pragma unroll
    for (int i = 0; i < 14; ++i) F[i] = (v8hf)(_Float16)0.f;
    float bb0 = 0.f, bb1 = 0.f, bb2 = 0.f;

    auto ldW = [&](const float* W, int rows, int cols, int j, int kt) -> v8hf {
        v8hf r;
        #pragma unroll
        for (int e = 0; e < 8; ++e) {
            const int k = kt * 32 + g * 8 + e;
            float v = (j < rows && k < cols) ? W[j * cols + k] : 0.f;
            r[e] = (_Float16)v;
        }
        return r;
    };
    auto ldW1 = [&](int j, int kt) -> v8hf {     // Whh1 (k<100) + x weights at k=112,113
        v8hf r;
        #pragma unroll
        for (int e = 0; e < 8; ++e) {
            const int k = kt * 32 + g * 8 + e;
            float v = 0.f;
            if (j < 100) {
                if (k < 100)       v = Whh1[j * 100 + k];
                else if (k == 112) v = Wih1[j * 2];
                else if (k == 113) v = Wih1[j * 2 + 1];
            }
            r[e] = (_Float16)v;
        }
        return r;
    };
    auto bL1 = [&](int j) -> float { return (j < 100) ? bih1[j] + bhh1[j] : 0.f; };
    auto bL2 = [&](int j) -> float { return (j < 60) ? bih2[j] + bhh2[j] : 0.f; };
    auto bL3 = [&](int j) -> float { return (j < 30) ? bih3[j] + bhh3[j] : 0.f; };

    // precomputed LDS byte offsets (parity-0 view; ^= PBLK each phase)
    unsigned oA = 0, oB = 0, oC = 0, oW1 = 0, oW2 = 0, oW3 = 0, oXw = 0, oRw = 0;

    if (wid < 4) {                     // heavy: L1 tile(wid) [+ tile(wid+4) if wid<3] + L2 tile(wid)
        const int jA = 16 * wid + col;             // L1 tile a & L2 tile share j-range
        #pragma unroll
        for (int kt = 0; kt < 4; ++kt) {
            F[0 + kt] = ldW1(jA, kt);
            F[8 + kt] = ldW(Wih2, 60, 100, jA, kt);
        }
        F[12] = ldW(Whh2, 60, 60, jA, 0);
        F[13] = ldW(Whh2, 60, 60, jA, 1);
        bb0 = bL1(jA); bb2 = bL2(jA);
        if (wid < 3) {
            const int jB = jA + 64;                // L1 tile b
            #pragma unroll
            for (int kt = 0; kt < 4; ++kt) F[4 + kt] = ldW1(jB, kt);
            bb1 = bL1(jB);
        }
        oA  = (unsigned)col * 272u + (unsigned)g * 16u;                    // h1[rp=0]
        oB  = PBLK + H2OFF + (unsigned)col * 144u + (unsigned)g * 16u;     // h2[wp=1]
        oW1 = PBLK + (unsigned)(4 * g) * 272u + (unsigned)jA * 2u;         // h1[wp=1]
        oW2 = H2OFF + (unsigned)(4 * g) * 144u + (unsigned)jA * 2u;        // h2[rp=0]
        oXw = PBLK + (unsigned)lane * 272u + 224u;                         // x into h1[wp]
    } else if (wid < 6) {              // light: L3 tile (wid-4)
        const int j3 = 16 * (wid - 4) + col;
        F[0] = ldW(Wih3, 30, 60, j3, 0);
        F[1] = ldW(Wih3, 30, 60, j3, 1);
        F[2] = ldW(Whh3, 30, 30, j3, 0);
        bb0 = bL3(j3);
        oB  = PBLK + H2OFF + (unsigned)col * 144u + (unsigned)g * 16u;     // h2[wp]
        oC  = H3OFF + (unsigned)col * 80u + (unsigned)g * 16u;             // h3[rp=0]
        oW3 = PBLK + H3OFF + (unsigned)(4 * g) * 80u + (unsigned)j3 * 2u;  // h3[wp=1]
    } else if (wid == 6) {             // light: head (W_eff = Wo2 @ Wo1, 2x30)
        #pragma unroll
        for (int e = 0; e < 8; ++e) {
            const int k = g * 8 + e;
            float v = 0.f;
            if (col < 2 && k < 30) {
                #pragma unroll
                for (int u = 0; u < 10; ++u) v += Wo2[col * 10 + u] * Wo1[u * 30 + k];
            }
            F[0][e] = (_Float16)v;
        }
        if (col < 2) {
            float bv = bo2[col];
            #pragma unroll
            for (int u = 0; u < 10; ++u) bv += Wo2[col * 10 + u] * bo1[u];
            bb0 = bv;
        }
        oC  = H3OFF + (unsigned)col * 80u + (unsigned)g * 16u;             // h3[rp=0]
        oRw = RINGO + (unsigned)(4 * g) * 512u + (unsigned)col * 4u;
    }                                   // wid 7: flush only

    __syncthreads();
    if (tid < BT)   // x_0 into h1 parity-0 block at k=112..113
        *(unsigned*)(SM + (unsigned)tid * 272u + 224u) =
            *(const unsigned*)(SM + XSTO + (unsigned)tid * 4u);
    __syncthreads();

#define ST_H1(r, EX) { \
    *(_Float16*)(SM + oW1 + (EX) + 0u)   = (_Float16)(r)[0]; \
    *(_Float16*)(SM + oW1 + (EX) + 272u) = (_Float16)(r)[1]; \
    *(_Float16*)(SM + oW1 + (EX) + 544u) = (_Float16)(r)[2]; \
    *(_Float16*)(SM + oW1 + (EX) + 816u) = (_Float16)(r)[3]; }
#define ST_H2(r) { \
    *(_Float16*)(SM + oW2 + 0u)   = (_Float16)(r)[0]; \
    *(_Float16*)(SM + oW2 + 144u) = (_Float16)(r)[1]; \
    *(_Float16*)(SM + oW2 + 288u) = (_Float16)(r)[2]; \
    *(_Float16*)(SM + oW2 + 432u) = (_Float16)(r)[3]; }
#define ST_H3(r) { \
    *(_Float16*)(SM + oW3 + 0u)   = (_Float16)(r)[0]; \
    *(_Float16*)(SM + oW3 + 80u)  = (_Float16)(r)[1]; \
    *(_Float16*)(SM + oW3 + 160u) = (_Float16)(r)[2]; \
    *(_Float16*)(SM + oW3 + 240u) = (_Float16)(r)[3]; }

    // ---------------- pipelined loop: one barrier per phase ----------------
    // phase s: L1(s) | L2(s-1) | L3(s-2) | head(s-3) | flush(32-block ending s-4)
    for (int s = 0; s < TT + 4; ++s) {
        if (wid < 4) {
            if (wid == 3 && lane < BT && s < TT - 1) {   // stage x_{s+1}
                unsigned xv = *(const unsigned*)(SM + XSTO + (unsigned)(s + 1) * 64u + (unsigned)lane * 4u);
                *(unsigned*)(SM + oXw) = xv;
            }
            if (s <= TT) {
                v8hf A0 = *(const v8hf*)(SM + oA);
                v8hf A1 = *(const v8hf*)(SM + oA + 64u);
                v8hf A2 = *(const v8hf*)(SM + oA + 128u);
                v8hf A3 = *(const v8hf*)(SM + oA + 192u);
                v8hf B0 = *(const v8hf*)(SM + oB);
                v8hf B1 = *(const v8hf*)(SM + oB + 64u);
                if (s < TT) {
                    {   // L1 tile a
                        v4f p = {bb0, bb0, bb0, bb0}, q = {0.f, 0.f, 0.f, 0.f};
                        p = MFMA16(A0, F[0], p); q = MFMA16(A1, F[1], q);
                        p = MFMA16(A2, F[2], p); q = MFMA16(A3, F[3], q);
                        v4f r = tanh4(p + q); ST_H1(r, 0u);
                    }
                    if (wid < 3) {   // L1 tile b (j+64)
                        v4f p = {bb1, bb1, bb1, bb1}, q = {0.f, 0.f, 0.f, 0.f};
                        p = MFMA16(A0, F[4], p); q = MFMA16(A1, F[5], q);
                        p = MFMA16(A2, F[6], p); q = MFMA16(A3, F[7], q);
                        v4f r = tanh4(p + q); ST_H1(r, 128u);
                    }
                }
                if (s >= 1) {    // L2 tile
                    v4f p = {bb2, bb2, bb2, bb2}, q = {0.f, 0.f, 0.f, 0.f};
                    p = MFMA16(A0, F[8],  p); q = MFMA16(A1, F[9],  q);
                    p = MFMA16(A2, F[10], p); q = MFMA16(A3, F[11], q);
                    p = MFMA16(B0, F[12], p); q = MFMA16(B1, F[13], q);
                    v4f r = tanh4(p + q); ST_H2(r);
                }
            }
            oA ^= PBLK; oB ^= PBLK; oW1 ^= PBLK; oW2 ^= PBLK; oXw ^= PBLK;
        } else if (wid < 6) {
            if (s >= 2 && s <= TT + 1) {   // L3 tile
                v8hf B0 = *(const v8hf*)(SM + oB);
                v8hf B1 = *(const v8hf*)(SM + oB + 64u);
                v8hf C0 = *(const v8hf*)(SM + oC);
                v4f p = {bb0, bb0, bb0, bb0}, q = {0.f, 0.f, 0.f, 0.f};
                p = MFMA16(B0, F[0], p); q = MFMA16(B1, F[1], q);
                p = MFMA16(C0, F[2], p);
                v4f r = tanh4(p + q); ST_H3(r);
            }
            oB ^= PBLK; oC ^= PBLK; oW3 ^= PBLK;
        } else if (wid == 6) {
            if (s >= 3 && s <= TT + 2) {   // head for t = s-3 -> ring
                v8hf C0 = *(const v8hf*)(SM + oC);
                v4f o = {bb0, bb0, bb0, bb0};
                o = MFMA16(C0, F[0], o);
                const unsigned so = ((unsigned)(s - 3) & 63u) * 8u;
                if (col < 2) {
                    *(float*)(SM + oRw + so + 0u)    = o[0];
                    *(float*)(SM + oRw + so + 512u)  = o[1];
                    *(float*)(SM + oRw + so + 1024u) = o[2];
                    *(float*)(SM + oRw + so + 1536u) = o[3];
                }
            }
            oC ^= PBLK;
        } else {
            if (s >= 35 && ((s - 4) & 31) == 31) {   // flush 32 head steps [s-35, s-4]
                const int tbase = s - 35;
                const unsigned rb = RINGO + (((unsigned)tbase & 63u) >> 1) * 16u;  // 0 or 512
                #pragma unroll
                for (int jj = 0; jj < 4; ++jj) {
                    const int f = lane + 64 * jj;        // 0..255
                    const int b = f >> 4, k = f & 15;
                    float4 v = *(const float4*)(SM + rb + (unsigned)b * 512u + (unsigned)k * 16u);
                    *(float4*)(outg + ((size_t)(bbase + b) * TT + tbase) * 2 + 4 * k) = v;
                }
            }
        }
        __syncthreads();
    }
}

extern "C" void kernel_launch(void* const* d_in, const int* in_sizes, int n_in,
                              void* d_out, int out_size, void* d_ws, size_t ws_size,
                              hipStream_t stream) {
    (void)in_sizes; (void)n_in; (void)d_ws; (void)ws_size; (void)out_size;
    const float* x     = (const float*)d_in[0];
    const float* W_ih1 = (const float*)d_in[1];
    const float* W_hh1 = (const float*)d_in[2];
    const float* b_ih1 = (const float*)d_in[3];
    const float* b_hh1 = (const float*)d_in[4];
    const float* W_ih2 = (const float*)d_in[5];
    const float* W_hh2 = (const float*)d_in[6];
    const float* b_ih2 = (const float*)d_in[7];
    const float* b_hh2 = (const float*)d_in[8];
    const float* W_ih3 = (const float*)d_in[9];
    const float* W_hh3 = (const float*)d_in[10];
    const float* b_ih3 = (const float*)d_in[11];
    const float* b_hh3 = (const float*)d_in[12];
    const float* W_o1  = (const float*)d_in[13];
    const float* b_o1  = (const float*)d_in[14];
    const float* W_o2  = (const float*)d_in[15];
    const float* b_o2  = (const float*)d_in[16];
    float* out = (float*)d_out;

    rnn3_hl<<<2048 / BT, NTH, 0, stream>>>(
        x, W_ih1, W_hh1, b_ih1, b_hh1,
        W_ih2, W_hh2, b_ih2, b_hh2,
        W_ih3, W_hh3, b_ih3, b_hh3,
        W_o1, b_o1, W_o2, b_o2, out);
}

// Round 7
// 307.538 us; speedup vs baseline: 1.2231x; 1.0130x over previous
//
#include <hip/hip_runtime.h>

typedef _Float16 v8hf __attribute__((ext_vector_type(8)));
typedef float    v4f  __attribute__((ext_vector_type(4)));

#define MFMA16(a, b, c) __builtin_amdgcn_mfma_f32_16x16x32_f16((a), (b), (c), 0, 0, 0)

#define TT 512
#define BT 16      // batch rows per workgroup (= MFMA M)
#define NTH 512    // 8 waves: w0-3 heavy(prio1), w4-7 light partners

// LDS map (bytes). Two 8KB parity blocks; parity folded into IMMEDIATE offsets.
//   block p at p*8192:  h1: +0    row stride 272 B (k: 0..99 h1, 100..111 fake, 112..113 x)
//                       h2: +4352 row stride 144 B
//                       h3: +6656 row stride  80 B
//   xst  at 16384: [t][b] f16x2, 64 B per t   (32 KB)
//   ring at 49152: [b][64][2] f32, 512 B per b (8 KB)
#define PBLK  8192u
#define H2OFF 4352u
#define H3OFF 6656u
#define XSTO  16384u
#define RINGO 49152u

__shared__ __align__(64) char SM[57344];

// batched tanh: 4 exp2 + 1 rcp per 4 values; med3 clamp |x|<=4.8 (err 1.35e-4).
__device__ __forceinline__ v4f tanh4(v4f r) {
    const float KS = 2.8853900817779268f;   // 2*log2(e)
    const float CL = 13.8498724f;           // 4.8 * KS
    float z0 = __builtin_amdgcn_fmed3f(r[0] * KS, -CL, CL);
    float z1 = __builtin_amdgcn_fmed3f(r[1] * KS, -CL, CL);
    float z2 = __builtin_amdgcn_fmed3f(r[2] * KS, -CL, CL);
    float z3 = __builtin_amdgcn_fmed3f(r[3] * KS, -CL, CL);
    float a0 = __builtin_amdgcn_exp2f(z0) + 1.f;
    float a1 = __builtin_amdgcn_exp2f(z1) + 1.f;
    float a2 = __builtin_amdgcn_exp2f(z2) + 1.f;
    float a3 = __builtin_amdgcn_exp2f(z3) + 1.f;
    float P = a0 * a1, Q = a2 * a3;
    float R = __builtin_amdgcn_rcpf(P * Q);
    float iP = Q * R, iQ = P * R;
    v4f t;
    t[0] = 1.f - 2.f * (a1 * iP);
    t[1] = 1.f - 2.f * (a0 * iP);
    t[2] = 1.f - 2.f * (a3 * iQ);
    t[3] = 1.f - 2.f * (a2 * iQ);
    return t;
}

__global__ __launch_bounds__(NTH)
void rnn3_sp(const float* __restrict__ xg,
             const float* __restrict__ Wih1, const float* __restrict__ Whh1,
             const float* __restrict__ bih1, const float* __restrict__ bhh1,
             const float* __restrict__ Wih2, const float* __restrict__ Whh2,
             const float* __restrict__ bih2, const float* __restrict__ bhh2,
             const float* __restrict__ Wih3, const float* __restrict__ Whh3,
             const float* __restrict__ bih3, const float* __restrict__ bhh3,
             const float* __restrict__ Wo1,  const float* __restrict__ bo1,
             const float* __restrict__ Wo2,  const float* __restrict__ bo2,
             float* __restrict__ outg)
{
    const int tid   = threadIdx.x;
    const int lane  = tid & 63;
    const int wid   = tid >> 6;       // SIMD = wid&3 -> pairs (0,4)(1,5)(2,6)(3,7)
    const int col   = lane & 15;
    const int g     = lane >> 4;
    const int bbase = blockIdx.x * BT;

    // ---------------- init: zero both parity state blocks, stage x ----------------
    {
        float4 z = {0.f, 0.f, 0.f, 0.f};
        float4* p4 = (float4*)SM;
        for (int i = tid; i < 1024; i += NTH) p4[i] = z;   // bytes [0, 16384)
        for (int i = tid; i < BT * TT * 2; i += NTH) {
            float v = xg[(size_t)bbase * (TT * 2) + i];
            int b = i >> 10, r = i & 1023, t = r >> 1, c = r & 1;
            *(_Float16*)(SM + XSTO + (unsigned)t * 64u + (unsigned)b * 4u + (unsigned)c * 2u) = (_Float16)v;
        }
    }

    // ---------------- weight fragments (registers) ----------------
    v8hf F[14];
    #pragma unroll
    for (int i = 0; i < 14; ++i) F[i] = (v8hf)(_Float16)0.f;
    float bb0 = 0.f, bb1 = 0.f, bb2 = 0.f;

    auto ldW = [&](const float* W, int rows, int cols, int j, int kt) -> v8hf {
        v8hf r;
        #pragma unroll
        for (int e = 0; e < 8; ++e) {
            const int k = kt * 32 + g * 8 + e;
            float v = (j < rows && k < cols) ? W[j * cols + k] : 0.f;
            r[e] = (_Float16)v;
        }
        return r;
    };
    auto ldW1 = [&](int j, int kt) -> v8hf {
        v8hf r;
        #pragma unroll
        for (int e = 0; e < 8; ++e) {
            const int k = kt * 32 + g * 8 + e;
            float v = 0.f;
            if (j < 100) {
                if (k < 100)       v = Whh1[j * 100 + k];
                else if (k == 112) v = Wih1[j * 2];
                else if (k == 113) v = Wih1[j * 2 + 1];
            }
            r[e] = (_Float16)v;
        }
        return r;
    };
    auto bL1 = [&](int j) -> float { return (j < 100) ? bih1[j] + bhh1[j] : 0.f; };
    auto bL2 = [&](int j) -> float { return (j < 60) ? bih2[j] + bhh2[j] : 0.f; };
    auto bL3 = [&](int j) -> float { return (j < 30) ? bih3[j] + bhh3[j] : 0.f; };

    unsigned bRd = 0, bRd2 = 0, bRd3 = 0, bW1 = 0, bW2 = 0, bW3 = 0, bXw = 0, bRw = 0;
    unsigned xr = 0;

    if (wid < 4) {                     // heavy: L1 tile(wid) [+ tile(wid+4) if wid<3] + L2 tile(wid)
        const int jA = 16 * wid + col;
        #pragma unroll
        for (int kt = 0; kt < 4; ++kt) {
            F[0 + kt] = ldW1(jA, kt);
            F[8 + kt] = ldW(Wih2, 60, 100, jA, kt);
        }
        F[12] = ldW(Whh2, 60, 60, jA, 0);
        F[13] = ldW(Whh2, 60, 60, jA, 1);
        bb0 = bL1(jA); bb2 = bL2(jA);
        if (wid < 3) {
            const int jB = jA + 64;
            #pragma unroll
            for (int kt = 0; kt < 4; ++kt) F[4 + kt] = ldW1(jB, kt);
            bb1 = bL1(jB);
        }
        bRd  = (unsigned)col * 272u + (unsigned)g * 16u;
        bRd2 = (unsigned)col * 144u + (unsigned)g * 16u;
        bW1  = (unsigned)(4 * g) * 272u + (unsigned)jA * 2u;
        bW2  = (unsigned)(4 * g) * 144u + (unsigned)jA * 2u;
    } else if (wid < 6) {              // light: L3 tile (wid-4)
        const int j3 = 16 * (wid - 4) + col;
        F[0] = ldW(Wih3, 30, 60, j3, 0);
        F[1] = ldW(Wih3, 30, 60, j3, 1);
        F[2] = ldW(Whh3, 30, 30, j3, 0);
        bb0 = bL3(j3);
        bRd2 = (unsigned)col * 144u + (unsigned)g * 16u;
        bRd3 = (unsigned)col * 80u + (unsigned)g * 16u;
        bW3  = (unsigned)(4 * g) * 80u + (unsigned)j3 * 2u;
    } else if (wid == 6) {             // light: head + x-stage
        #pragma unroll
        for (int e = 0; e < 8; ++e) {  // W_eff = Wo2 @ Wo1 (2 x 30)
            const int k = g * 8 + e;
            float v = 0.f;
            if (col < 2 && k < 30) {
                #pragma unroll
                for (int u = 0; u < 10; ++u) v += Wo2[col * 10 + u] * Wo1[u * 30 + k];
            }
            F[0][e] = (_Float16)v;
        }
        if (col < 2) {
            float bv = bo2[col];
            #pragma unroll
            for (int u = 0; u < 10; ++u) bv += Wo2[col * 10 + u] * bo1[u];
            bb0 = bv;
        }
        bRd3 = (unsigned)col * 80u + (unsigned)g * 16u;
        bXw  = (unsigned)lane * 272u + 224u;
        xr   = XSTO + 64u + (unsigned)lane * 4u;
        bRw  = RINGO + (unsigned)(4 * g) * 512u + (unsigned)col * 4u;
    }                                   // wid 7: flush only

    __syncthreads();
    if (tid < BT)   // x_0 into h1 parity-0 block at k=112..113
        *(unsigned*)(SM + (unsigned)tid * 272u + 224u) =
            *(const unsigned*)(SM + XSTO + (unsigned)tid * 4u);
    __syncthreads();

    if (wid < 4) __builtin_amdgcn_s_setprio(1);   // heavy waves keep priority for the whole loop

    auto flushfn = [&](int s) {        // w7: flush 32 head steps [s-35, s-4]
        const int tbase = s - 35;
        const unsigned rb = RINGO + (((unsigned)tbase & 63u) >> 1) * 16u;
        #pragma unroll
        for (int jj = 0; jj < 4; ++jj) {
            const int f = lane + 64 * jj;
            const int b = f >> 4, k = f & 15;
            float4 v = *(const float4*)(SM + rb + (unsigned)b * 512u + (unsigned)k * 16u);
            *(float4*)(outg + ((size_t)(bbase + b) * TT + tbase) * 2 + 4 * k) = v;
        }
    };

// phase S (parity RP): L1(S) | L2(S-1) | L3(S-2) | head(S-3) | stage x_{S+1} | flush
#define PHASE(RP, L1ON, L2ON, L3ON, HDON, XON, S) do {                                   \
    const unsigned RB_ = (RP) ? PBLK : 0u;                                               \
    const unsigned WB_ = (RP) ? 0u : PBLK;                                               \
    if (wid < 4) {                                                                       \
        if ((L1ON) || (L2ON)) {                                                          \
            v8hf A0 = *(const v8hf*)(SM + bRd + RB_ + 0u);                               \
            v8hf A1 = *(const v8hf*)(SM + bRd + RB_ + 64u);                              \
            v8hf A2 = *(const v8hf*)(SM + bRd + RB_ + 128u);                             \
            v8hf A3 = *(const v8hf*)(SM + bRd + RB_ + 192u);                             \
            if (L1ON) {                                                                  \
                { v4f p = {bb0, bb0, bb0, bb0}, q = {0.f, 0.f, 0.f, 0.f};                \
                  p = MFMA16(A0, F[0], p); q = MFMA16(A1, F[1], q);                      \
                  p = MFMA16(A2, F[2], p); q = MFMA16(A3, F[3], q);                      \
                  v4f r = tanh4(p + q);                                                  \
                  *(_Float16*)(SM + bW1 + WB_ + 0u)   = (_Float16)r[0];                  \
                  *(_Float16*)(SM + bW1 + WB_ + 272u) = (_Float16)r[1];                  \
                  *(_Float16*)(SM + bW1 + WB_ + 544u) = (_Float16)r[2];                  \
                  *(_Float16*)(SM + bW1 + WB_ + 816u) = (_Float16)r[3]; }                \
                if (wid < 3) {                                                           \
                  v4f p = {bb1, bb1, bb1, bb1}, q = {0.f, 0.f, 0.f, 0.f};                \
                  p = MFMA16(A0, F[4], p); q = MFMA16(A1, F[5], q);                      \
                  p = MFMA16(A2, F[6], p); q = MFMA16(A3, F[7], q);                      \
                  v4f r = tanh4(p + q);                                                  \
                  *(_Float16*)(SM + bW1 + WB_ + 128u)  = (_Float16)r[0];                 \
                  *(_Float16*)(SM + bW1 + WB_ + 400u)  = (_Float16)r[1];                 \
                  *(_Float16*)(SM + bW1 + WB_ + 672u)  = (_Float16)r[2];                 \
                  *(_Float16*)(SM + bW1 + WB_ + 944u)  = (_Float16)r[3]; }               \
            }                                                                            \
            if (L2ON) {                                                                  \
                v8hf B0 = *(const v8hf*)(SM + bRd2 + WB_ + H2OFF + 0u);                  \
                v8hf B1 = *(const v8hf*)(SM + bRd2 + WB_ + H2OFF + 64u);                 \
                v4f p = {bb2, bb2, bb2, bb2}, q = {0.f, 0.f, 0.f, 0.f};                  \
                p = MFMA16(A0, F[8],  p); q = MFMA16(A1, F[9],  q);                      \
                p = MFMA16(A2, F[10], p); q = MFMA16(A3, F[11], q);                      \
                p = MFMA16(B0, F[12], p); q = MFMA16(B1, F[13], q);                      \
                v4f r = tanh4(p + q);                                                    \
                *(_Float16*)(SM + bW2 + RB_ + H2OFF + 0u)   = (_Float16)r[0];            \
                *(_Float16*)(SM + bW2 + RB_ + H2OFF + 144u) = (_Float16)r[1];            \
                *(_Float16*)(SM + bW2 + RB_ + H2OFF + 288u) = (_Float16)r[2];            \
                *(_Float16*)(SM + bW2 + RB_ + H2OFF + 432u) = (_Float16)r[3];            \
            }                                                                            \
        }                                                                                \
    } else if (wid < 6) {                                                                \
        if (L3ON) {                                                                      \
            v8hf B0 = *(const v8hf*)(SM + bRd2 + WB_ + H2OFF + 0u);                      \
            v8hf B1 = *(const v8hf*)(SM + bRd2 + WB_ + H2OFF + 64u);                     \
            v8hf C0 = *(const v8hf*)(SM + bRd3 + RB_ + H3OFF);                           \
            v4f p = {bb0, bb0, bb0, bb0}, q = {0.f, 0.f, 0.f, 0.f};                      \
            p = MFMA16(B0, F[0], p); q = MFMA16(B1, F[1], q);                            \
            p = MFMA16(C0, F[2], p);                                                     \
            v4f r = tanh4(p + q);                                                        \
            *(_Float16*)(SM + bW3 + WB_ + H3OFF + 0u)   = (_Float16)r[0];                \
            *(_Float16*)(SM + bW3 + WB_ + H3OFF + 80u)  = (_Float16)r[1];                \
            *(_Float16*)(SM + bW3 + WB_ + H3OFF + 160u) = (_Float16)r[2];                \
            *(_Float16*)(SM + bW3 + WB_ + H3OFF + 240u) = (_Float16)r[3];                \
        }                                                                                \
    } else if (wid == 6) {                                                               \
        if (XON) {                                                                       \
            if (lane < 16) {                                                             \
                unsigned xv = *(const unsigned*)(SM + xr);                               \
                *(unsigned*)(SM + bXw + WB_) = xv;                                       \
            }                                                                            \
        }                                                                                \
        xr += 64u;                                                                       \
        if (HDON) {                                                                      \
            v8hf C0 = *(const v8hf*)(SM + bRd3 + RB_ + H3OFF);                           \
            v4f o = {bb0, bb0, bb0, bb0};                                                \
            o = MFMA16(C0, F[0], o);                                                     \
            const unsigned so = (((unsigned)(S) - 3u) & 63u) * 8u;                       \
            if (col < 2) {                                                               \
                *(float*)(SM + bRw + so + 0u)    = o[0];                                 \
                *(float*)(SM + bRw + so + 512u)  = o[1];                                 \
                *(float*)(SM + bRw + so + 1024u) = o[2];                                 \
                *(float*)(SM + bRw + so + 1536u) = o[3];                                 \
            }                                                                            \
        }                                                                                \
    } else {                                                                             \
        if ((S) >= 35 && (((S) - 4) & 31) == 31) flushfn((S));                           \
    }                                                                                    \
    __syncthreads();                                                                     \
} while (0)

    // prologue (guarded pipeline fill)
    PHASE(0, 1, 0, 0, 0, 1, 0);
    PHASE(1, 1, 1, 0, 0, 1, 1);
    PHASE(0, 1, 1, 1, 0, 1, 2);
    PHASE(1, 1, 1, 1, 1, 1, 3);
    // steady state: guard-free, compile-time parity
    for (int s = 4; s < 510; s += 2) {
        PHASE(0, 1, 1, 1, 1, 1, s);
        PHASE(1, 1, 1, 1, 1, 1, s + 1);
    }
    // epilogue (guarded pipeline drain)
    PHASE(0, 1, 1, 1, 1, 1, 510);
    PHASE(1, 1, 1, 1, 1, 0, 511);
    PHASE(0, 0, 1, 1, 1, 0, 512);
    PHASE(1, 0, 0, 1, 1, 0, 513);
    PHASE(0, 0, 0, 0, 1, 0, 514);
    PHASE(1, 0, 0, 0, 0, 0, 515);
}

extern "C" void kernel_launch(void* const* d_in, const int* in_sizes, int n_in,
                              void* d_out, int out_size, void* d_ws, size_t ws_size,
                              hipStream_t stream) {
    (void)in_sizes; (void)n_in; (void)d_ws; (void)ws_size; (void)out_size;
    const float* x     = (const float*)d_in[0];
    const float* W_ih1 = (const float*)d_in[1];
    const float* W_hh1 = (const float*)d_in[2];
    const float* b_ih1 = (const float*)d_in[3];
    const float* b_hh1 = (const float*)d_in[4];
    const float* W_ih2 = (const float*)d_in[5];
    const float* W_hh2 = (const float*)d_in[6];
    const float* b_ih2 = (const float*)d_in[7];
    const float* b_hh2 = (const float*)d_in[8];
    const float* W_ih3 = (const float*)d_in[9];
    const float* W_hh3 = (const float*)d_in[10];
    const float* b_ih3 = (const float*)d_in[11];
    const float* b_hh3 = (const float*)d_in[12];
    const float* W_o1  = (const float*)d_in[13];
    const float* b_o1  = (const float*)d_in[14];
    const float* W_o2  = (const float*)d_in[15];
    const float* b_o2  = (const float*)d_in[16];
    float* out = (float*)d_out;

    rnn3_sp<<<2048 / BT, NTH, 0, stream>>>(
        x, W_ih1, W_hh1, b_ih1, b_hh1,
        W_ih2, W_hh2, b_ih2, b_hh2,
        W_ih3, W_hh3, b_ih3, b_hh3,
        W_o1, b_o1, W_o2, b_o2, out);
}

// Round 8
// 291.807 us; speedup vs baseline: 1.2891x; 1.0539x over previous
//
#include <hip/hip_runtime.h>

typedef _Float16 v8hf __attribute__((ext_vector_type(8)));
typedef float    v4f  __attribute__((ext_vector_type(4)));

#define MFMA16(a, b, c) __builtin_amdgcn_mfma_f32_16x16x32_f16((a), (b), (c), 0, 0, 0)

#define TT 512
#define BT 16       // batch rows per workgroup (= MFMA M)
#define NTH 1024    // 16 waves, 4 per SIMD, one tile each

// LDS map (bytes). Two 8KB parity blocks; parity folded into IMMEDIATE offsets.
//   block p at p*8192:  h1: +0    row stride 272 B (k: 0..99 h1, 100..111 fake, 112..113 x)
//                       h2: +4352 row stride 144 B
//                       h3: +6656 row stride  80 B
//   xst  at 16384: [t][b] f16x2, 64 B per t   (32 KB)
//   ring at 49152: [b][64][2] f32, 512 B per b (8 KB)
#define PBLK  8192u
#define H2OFF 4352u
#define H3OFF 6656u
#define XSTO  16384u
#define RINGO 49152u

__shared__ __align__(64) char SM[57344];

// batched tanh: 4 exp2 + 1 rcp per 4 values; med3 clamp |x|<=4.8 (err 1.35e-4).
__device__ __forceinline__ v4f tanh4(v4f r) {
    const float KS = 2.8853900817779268f;   // 2*log2(e)
    const float CL = 13.8498724f;           // 4.8 * KS
    float z0 = __builtin_amdgcn_fmed3f(r[0] * KS, -CL, CL);
    float z1 = __builtin_amdgcn_fmed3f(r[1] * KS, -CL, CL);
    float z2 = __builtin_amdgcn_fmed3f(r[2] * KS, -CL, CL);
    float z3 = __builtin_amdgcn_fmed3f(r[3] * KS, -CL, CL);
    float a0 = __builtin_amdgcn_exp2f(z0) + 1.f;
    float a1 = __builtin_amdgcn_exp2f(z1) + 1.f;
    float a2 = __builtin_amdgcn_exp2f(z2) + 1.f;
    float a3 = __builtin_amdgcn_exp2f(z3) + 1.f;
    float P = a0 * a1, Q = a2 * a3;
    float R = __builtin_amdgcn_rcpf(P * Q);
    float iP = Q * R, iQ = P * R;
    v4f t;
    t[0] = 1.f - 2.f * (a1 * iP);
    t[1] = 1.f - 2.f * (a0 * iP);
    t[2] = 1.f - 2.f * (a3 * iQ);
    t[3] = 1.f - 2.f * (a2 * iQ);
    return t;
}

__global__ __launch_bounds__(NTH)
void rnn3_t16(const float* __restrict__ xg,
              const float* __restrict__ Wih1, const float* __restrict__ Whh1,
              const float* __restrict__ bih1, const float* __restrict__ bhh1,
              const float* __restrict__ Wih2, const float* __restrict__ Whh2,
              const float* __restrict__ bih2, const float* __restrict__ bhh2,
              const float* __restrict__ Wih3, const float* __restrict__ Whh3,
              const float* __restrict__ bih3, const float* __restrict__ bhh3,
              const float* __restrict__ Wo1,  const float* __restrict__ bo1,
              const float* __restrict__ Wo2,  const float* __restrict__ bo2,
              float* __restrict__ outg)
{
    const int tid   = threadIdx.x;
    const int lane  = tid & 63;
    const int wid   = tid >> 6;       // wave 0..15; SIMD = wid&3
    const int col   = lane & 15;
    const int g     = lane >> 4;
    const int bbase = blockIdx.x * BT;

    // ---------------- init: zero both parity state blocks, stage x ----------------
    {
        float4 z = {0.f, 0.f, 0.f, 0.f};
        float4* p4 = (float4*)SM;
        for (int i = tid; i < 1024; i += NTH) p4[i] = z;   // bytes [0, 16384)
        for (int i = tid; i < BT * TT * 2; i += NTH) {
            float v = xg[(size_t)bbase * (TT * 2) + i];
            int b = i >> 10, r = i & 1023, t = r >> 1, c = r & 1;
            *(_Float16*)(SM + XSTO + (unsigned)t * 64u + (unsigned)b * 4u + (unsigned)c * 2u) = (_Float16)v;
        }
    }

    // ---------------- weight fragments (registers) ----------------
    // B-frag convention: (lane,e) = W[j][k], j = tile_base + col, k = kt*32 + g*8 + e.
    v8hf F[6];
    #pragma unroll
    for (int i = 0; i < 6; ++i) F[i] = (v8hf)(_Float16)0.f;
    float bb0 = 0.f;

    auto ldW = [&](const float* W, int rows, int cols, int j, int kt) -> v8hf {
        v8hf r;
        #pragma unroll
        for (int e = 0; e < 8; ++e) {
            const int k = kt * 32 + g * 8 + e;
            float v = (j < rows && k < cols) ? W[j * cols + k] : 0.f;
            r[e] = (_Float16)v;
        }
        return r;
    };
    auto ldW1 = [&](int j, int kt) -> v8hf {
        v8hf r;
        #pragma unroll
        for (int e = 0; e < 8; ++e) {
            const int k = kt * 32 + g * 8 + e;
            float v = 0.f;
            if (j < 100) {
                if (k < 100)       v = Whh1[j * 100 + k];
                else if (k == 112) v = Wih1[j * 2];
                else if (k == 113) v = Wih1[j * 2 + 1];
            }
            r[e] = (_Float16)v;
        }
        return r;
    };

    unsigned bRd = 0, bRd2 = 0, bRd3 = 0, bW1 = 0, bW2 = 0, bW3 = 0, bXw = 0, bRw = 0;
    unsigned xr = 0;

    if (wid < 7) {                     // L1 tile wid
        const int jA = 16 * wid + col;
        #pragma unroll
        for (int kt = 0; kt < 4; ++kt) F[kt] = ldW1(jA, kt);
        bb0 = (jA < 100) ? bih1[jA] + bhh1[jA] : 0.f;
        bRd = (unsigned)col * 272u + (unsigned)g * 16u;
        bW1 = (unsigned)(4 * g) * 272u + (unsigned)jA * 2u;
    } else if (wid == 7) {             // x-stage
        bXw = (unsigned)lane * 272u + 224u;
        xr  = XSTO + 64u + (unsigned)lane * 4u;
    } else if (wid < 12) {             // L2 tile (wid-8)
        const int j2 = 16 * (wid - 8) + col;
        #pragma unroll
        for (int kt = 0; kt < 4; ++kt) F[kt] = ldW(Wih2, 60, 100, j2, kt);
        F[4] = ldW(Whh2, 60, 60, j2, 0);
        F[5] = ldW(Whh2, 60, 60, j2, 1);
        bb0 = (j2 < 60) ? bih2[j2] + bhh2[j2] : 0.f;
        bRd  = (unsigned)col * 272u + (unsigned)g * 16u;
        bRd2 = (unsigned)col * 144u + (unsigned)g * 16u;
        bW2  = (unsigned)(4 * g) * 144u + (unsigned)j2 * 2u;
    } else if (wid < 14) {             // L3 tile (wid-12)
        const int j3 = 16 * (wid - 12) + col;
        F[0] = ldW(Wih3, 30, 60, j3, 0);
        F[1] = ldW(Wih3, 30, 60, j3, 1);
        F[2] = ldW(Whh3, 30, 30, j3, 0);
        bb0 = (j3 < 30) ? bih3[j3] + bhh3[j3] : 0.f;
        bRd2 = (unsigned)col * 144u + (unsigned)g * 16u;
        bRd3 = (unsigned)col * 80u + (unsigned)g * 16u;
        bW3  = (unsigned)(4 * g) * 80u + (unsigned)j3 * 2u;
    } else if (wid == 14) {            // head: W_eff = Wo2 @ Wo1 (2 x 30)
        #pragma unroll
        for (int e = 0; e < 8; ++e) {
            const int k = g * 8 + e;
            float v = 0.f;
            if (col < 2 && k < 30) {
                #pragma unroll
                for (int u = 0; u < 10; ++u) v += Wo2[col * 10 + u] * Wo1[u * 30 + k];
            }
            F[0][e] = (_Float16)v;
        }
        if (col < 2) {
            float bv = bo2[col];
            #pragma unroll
            for (int u = 0; u < 10; ++u) bv += Wo2[col * 10 + u] * bo1[u];
            bb0 = bv;
        }
        bRd3 = (unsigned)col * 80u + (unsigned)g * 16u;
        bRw  = RINGO + (unsigned)(4 * g) * 512u + (unsigned)col * 4u;
    }                                   // wid 15: flush only

    __syncthreads();
    if (tid < BT)   // x_0 into h1 parity-0 block at k=112..113
        *(unsigned*)(SM + (unsigned)tid * 272u + 224u) =
            *(const unsigned*)(SM + XSTO + (unsigned)tid * 4u);
    __syncthreads();

    auto flushfn = [&](int s) {        // w15: flush 32 head steps [s-35, s-4]
        const int tbase = s - 35;
        const unsigned rb = RINGO + (((unsigned)tbase & 63u) >> 1) * 16u;
        #pragma unroll
        for (int jj = 0; jj < 4; ++jj) {
            const int f = lane + 64 * jj;
            const int b = f >> 4, k = f & 15;
            float4 v = *(const float4*)(SM + rb + (unsigned)b * 512u + (unsigned)k * 16u);
            *(float4*)(outg + ((size_t)(bbase + b) * TT + tbase) * 2 + 4 * k) = v;
        }
    };

// phase S (parity RP): L1(S) | L2(S-1) | L3(S-2) | head(S-3) | stage x_{S+1} | flush
#define PHASE(RP, L1ON, L2ON, L3ON, HDON, XON, S) do {                                   \
    const unsigned RB_ = (RP) ? PBLK : 0u;                                               \
    const unsigned WB_ = (RP) ? 0u : PBLK;                                               \
    if (wid < 7) {                                                                       \
        if (L1ON) {                                                                      \
            v8hf A0 = *(const v8hf*)(SM + bRd + RB_ + 0u);                               \
            v8hf A1 = *(const v8hf*)(SM + bRd + RB_ + 64u);                              \
            v8hf A2 = *(const v8hf*)(SM + bRd + RB_ + 128u);                             \
            v8hf A3 = *(const v8hf*)(SM + bRd + RB_ + 192u);                             \
            v4f p = {bb0, bb0, bb0, bb0}, q = {0.f, 0.f, 0.f, 0.f};                      \
            p = MFMA16(A0, F[0], p); q = MFMA16(A1, F[1], q);                            \
            p = MFMA16(A2, F[2], p); q = MFMA16(A3, F[3], q);                            \
            v4f r = tanh4(p + q);                                                        \
            *(_Float16*)(SM + bW1 + WB_ + 0u)   = (_Float16)r[0];                        \
            *(_Float16*)(SM + bW1 + WB_ + 272u) = (_Float16)r[1];                        \
            *(_Float16*)(SM + bW1 + WB_ + 544u) = (_Float16)r[2];                        \
            *(_Float16*)(SM + bW1 + WB_ + 816u) = (_Float16)r[3];                        \
        }                                                                                \
    } else if (wid == 7) {                                                               \
        if (XON) {                                                                       \
            if (lane < 16) {                                                             \
                unsigned xv = *(const unsigned*)(SM + xr);                               \
                *(unsigned*)(SM + bXw + WB_) = xv;                                       \
            }                                                                            \
        }                                                                                \
        xr += 64u;                                                                       \
    } else if (wid < 12) {                                                               \
        if (L2ON) {                                                                      \
            v8hf A0 = *(const v8hf*)(SM + bRd + RB_ + 0u);                               \
            v8hf A1 = *(const v8hf*)(SM + bRd + RB_ + 64u);                              \
            v8hf A2 = *(const v8hf*)(SM + bRd + RB_ + 128u);                             \
            v8hf A3 = *(const v8hf*)(SM + bRd + RB_ + 192u);                             \
            v8hf B0 = *(const v8hf*)(SM + bRd2 + WB_ + H2OFF + 0u);                      \
            v8hf B1 = *(const v8hf*)(SM + bRd2 + WB_ + H2OFF + 64u);                     \
            v4f p = {bb0, bb0, bb0, bb0}, q = {0.f, 0.f, 0.f, 0.f};                      \
            p = MFMA16(A0, F[0], p); q = MFMA16(A1, F[1], q);                            \
            p = MFMA16(A2, F[2], p); q = MFMA16(A3, F[3], q);                            \
            p = MFMA16(B0, F[4], p); q = MFMA16(B1, F[5], q);                            \
            v4f r = tanh4(p + q);                                                        \
            *(_Float16*)(SM + bW2 + RB_ + H2OFF + 0u)   = (_Float16)r[0];                \
            *(_Float16*)(SM + bW2 + RB_ + H2OFF + 144u) = (_Float16)r[1];                \
            *(_Float16*)(SM + bW2 + RB_ + H2OFF + 288u) = (_Float16)r[2];                \
            *(_Float16*)(SM + bW2 + RB_ + H2OFF + 432u) = (_Float16)r[3];                \
        }                                                                                \
    } else if (wid < 14) {                                                               \
        if (L3ON) {                                                                      \
            v8hf B0 = *(const v8hf*)(SM + bRd2 + WB_ + H2OFF + 0u);                      \
            v8hf B1 = *(const v8hf*)(SM + bRd2 + WB_ + H2OFF + 64u);                     \
            v8hf C0 = *(const v8hf*)(SM + bRd3 + RB_ + H3OFF);                           \
            v4f p = {bb0, bb0, bb0, bb0}, q = {0.f, 0.f, 0.f, 0.f};                      \
            p = MFMA16(B0, F[0], p); q = MFMA16(B1, F[1], q);                            \
            p = MFMA16(C0, F[2], p);                                                     \
            v4f r = tanh4(p + q);                                                        \
            *(_Float16*)(SM + bW3 + WB_ + H3OFF + 0u)   = (_Float16)r[0];                \
            *(_Float16*)(SM + bW3 + WB_ + H3OFF + 80u)  = (_Float16)r[1];                \
            *(_Float16*)(SM + bW3 + WB_ + H3OFF + 160u) = (_Float16)r[2];                \
            *(_Float16*)(SM + bW3 + WB_ + H3OFF + 240u) = (_Float16)r[3];                \
        }                                                                                \
    } else if (wid == 14) {                                                              \
        if (HDON) {                                                                      \
            v8hf C0 = *(const v8hf*)(SM + bRd3 + RB_ + H3OFF);                           \
            v4f o = {bb0, bb0, bb0, bb0};                                                \
            o = MFMA16(C0, F[0], o);                                                     \
            const unsigned so = (((unsigned)(S) - 3u) & 63u) * 8u;                       \
            if (col < 2) {                                                               \
                *(float*)(SM + bRw + so + 0u)    = o[0];                                 \
                *(float*)(SM + bRw + so + 512u)  = o[1];                                 \
                *(float*)(SM + bRw + so + 1024u) = o[2];                                 \
                *(float*)(SM + bRw + so + 1536u) = o[3];                                 \
            }                                                                            \
        }                                                                                \
    } else {                                                                             \
        if ((S) >= 35 && (((S) - 4) & 31) == 31) flushfn((S));                           \
    }                                                                                    \
    __syncthreads();                                                                     \
} while (0)

    // prologue (guarded pipeline fill)
    PHASE(0, 1, 0, 0, 0, 1, 0);
    PHASE(1, 1, 1, 0, 0, 1, 1);
    PHASE(0, 1, 1, 1, 0, 1, 2);
    PHASE(1, 1, 1, 1, 1, 1, 3);
    // steady state: guard-free, compile-time parity
    for (int s = 4; s < 510; s += 2) {
        PHASE(0, 1, 1, 1, 1, 1, s);
        PHASE(1, 1, 1, 1, 1, 1, s + 1);
    }
    // epilogue (guarded pipeline drain)
    PHASE(0, 1, 1, 1, 1, 1, 510);
    PHASE(1, 1, 1, 1, 1, 0, 511);
    PHASE(0, 0, 1, 1, 1, 0, 512);
    PHASE(1, 0, 0, 1, 1, 0, 513);
    PHASE(0, 0, 0, 0, 1, 0, 514);
    PHASE(1, 0, 0, 0, 0, 0, 515);
}

extern "C" void kernel_launch(void* const* d_in, const int* in_sizes, int n_in,
                              void* d_out, int out_size, void* d_ws, size_t ws_size,
                              hipStream_t stream) {
    (void)in_sizes; (void)n_in; (void)d_ws; (void)ws_size; (void)out_size;
    const float* x     = (const float*)d_in[0];
    const float* W_ih1 = (const float*)d_in[1];
    const float* W_hh1 = (const float*)d_in[2];
    const float* b_ih1 = (const float*)d_in[3];
    const float* b_hh1 = (const float*)d_in[4];
    const float* W_ih2 = (const float*)d_in[5];
    const float* W_hh2 = (const float*)d_in[6];
    const float* b_ih2 = (const float*)d_in[7];
    const float* b_hh2 = (const float*)d_in[8];
    const float* W_ih3 = (const float*)d_in[9];
    const float* W_hh3 = (const float*)d_in[10];
    const float* b_ih3 = (const float*)d_in[11];
    const float* b_hh3 = (const float*)d_in[12];
    const float* W_o1  = (const float*)d_in[13];
    const float* b_o1  = (const float*)d_in[14];
    const float* W_o2  = (const float*)d_in[15];
    const float* b_o2  = (const float*)d_in[16];
    float* out = (float*)d_out;

    rnn3_t16<<<2048 / BT, NTH, 0, stream>>>(
        x, W_ih1, W_hh1, b_ih1, b_hh1,
        W_ih2, W_hh2, b_ih2, b_hh2,
        W_ih3, W_hh3, b_ih3, b_hh3,
        W_o1, b_o1, W_o2, b_o2, out);
}